// Round 1
// baseline (494.590 us; speedup 1.0000x reference)
//
#include <hip/hip_runtime.h>

#define V 12288
#define CIN 16
#define COUT 32
#define NK 5
#define SSPLIT 8
#define UCHUNK (V / SSPLIT)   // 1536

typedef _Float16 half8 __attribute__((ext_vector_type(8)));
typedef float f32x4 __attribute__((ext_vector_type(4)));

// ---- x (f32) -> fp16 ------------------------------------------------------
__global__ __launch_bounds__(256) void x_to_h(const float* __restrict__ x,
                                              _Float16* __restrict__ Th) {
    int i = blockIdx.x * 256 + threadIdx.x;   // CIN*V = 196608 exact
    Th[i] = (_Float16)x[i];
}

// ---- partial GEMM: partials[uc][i][v] = sum_{u in chunk} A[i][u] * L[v][u] -
// One wave owns one 16x16 (i x v) output tile for one u-chunk.
// Fragments loaded straight from global: lane l reads row (l&15), cols
// u + (l>>4)*8 .. +7  (16B). Same k-mapping for A and B => any HW K
// permutation cancels. C/D: i = (l>>4)*4 + r, v = v0 + (l&15)  [m89].
template<bool LF32, bool WLH>
__global__ __launch_bounds__(256) void cheb_mm(
    const _Float16* __restrict__ Ah,      // (CIN,V) fp16
    const float*    __restrict__ Lf,      // (V,V) f32   (if LF32)
    const _Float16* __restrict__ Lh,      // (V,V) fp16  (if !LF32)
    _Float16*       __restrict__ Lh_out,  // written if WLH
    float*          __restrict__ partials)// (SSPLIT,CIN,V)
{
    const int wave = threadIdx.x >> 6;
    const int lane = threadIdx.x & 63;
    const int lr = lane & 15;
    const int hi = lane >> 4;
    const int v0 = (blockIdx.x * 4 + wave) * 16;   // 192*4 = 768 v-tiles
    const int u0 = blockIdx.y * UCHUNK;

    const _Float16* ap = Ah + (size_t)lr * V + u0 + hi * 8;
    f32x4 acc = {0.f, 0.f, 0.f, 0.f};

    if constexpr (LF32) {
        const float* lp = Lf + (size_t)(v0 + lr) * V + u0 + hi * 8;
        _Float16* lo = nullptr;
        if constexpr (WLH) lo = Lh_out + (size_t)(v0 + lr) * V + u0 + hi * 8;
        #pragma unroll 4
        for (int u = 0; u < UCHUNK; u += 32) {
            half8 a = *(const half8*)(ap + u);
            f32x4 f0 = *(const f32x4*)(lp + u);
            f32x4 f1 = *(const f32x4*)(lp + u + 4);
            half8 b;
            #pragma unroll
            for (int j = 0; j < 4; ++j) {
                b[j]     = (_Float16)f0[j];
                b[j + 4] = (_Float16)f1[j];
            }
            if constexpr (WLH) *(half8*)(lo + u) = b;
            acc = __builtin_amdgcn_mfma_f32_16x16x32_f16(a, b, acc, 0, 0, 0);
        }
    } else {
        const _Float16* lp = Lh + (size_t)(v0 + lr) * V + u0 + hi * 8;
        #pragma unroll 4
        for (int u = 0; u < UCHUNK; u += 32) {
            half8 a = *(const half8*)(ap + u);
            half8 b = *(const half8*)(lp + u);
            acc = __builtin_amdgcn_mfma_f32_16x16x32_f16(a, b, acc, 0, 0, 0);
        }
    }

    float* pp = partials + ((size_t)blockIdx.y * CIN + hi * 4) * V + v0 + lr;
    pp[0]            = acc[0];
    pp[(size_t)V]    = acc[1];
    pp[(size_t)2*V]  = acc[2];
    pp[(size_t)3*V]  = acc[3];
}

// ---- reduce partials, apply recurrence, emit f32 + fp16 -------------------
__global__ __launch_bounds__(256) void cheb_reduce(
    const float* __restrict__ partials,
    const float* __restrict__ Tm2,        // T_{k-2} (f32), unused for k==1
    float*       __restrict__ Tk,
    _Float16*    __restrict__ Th,
    int k)
{
    int i = blockIdx.x * 256 + threadIdx.x;   // CIN*V exact
    float s = 0.f;
    #pragma unroll
    for (int j = 0; j < SSPLIT; ++j) s += partials[(size_t)j * CIN * V + i];
    float t = (k == 1) ? s : 2.f * s - Tm2[i];
    Tk[i] = t;
    Th[i] = (_Float16)t;
}

// ---- out(o,v) = bias(o) + sum_k sum_i T_k(i,v) * W(k,i,o) -----------------
__global__ __launch_bounds__(256) void cheb_out_k(
    const float* __restrict__ x,      // T_0
    const float* __restrict__ T14,    // T_1..T_4, (4,CIN,V)
    const float* __restrict__ W,      // (NK,CIN,COUT)
    const float* __restrict__ bias,
    float* __restrict__ out)
{
    int v = blockIdx.x * 256 + threadIdx.x;
    int o = blockIdx.y;
    float acc = bias[o];
    #pragma unroll
    for (int i = 0; i < CIN; ++i)
        acc += x[(size_t)i * V + v] * W[i * COUT + o];
    #pragma unroll
    for (int k = 1; k < NK; ++k)
        #pragma unroll
        for (int i = 0; i < CIN; ++i)
            acc += T14[((size_t)(k - 1) * CIN + i) * V + v] * W[(k * CIN + i) * COUT + o];
    out[(size_t)o * V + v] = acc;
}

extern "C" void kernel_launch(void* const* d_in, const int* in_sizes, int n_in,
                              void* d_out, int out_size, void* d_ws, size_t ws_size,
                              hipStream_t stream) {
    const float* x    = (const float*)d_in[0];
    const float* L    = (const float*)d_in[1];
    const float* W    = (const float*)d_in[2];
    const float* bias = (const float*)d_in[3];
    float* out = (float*)d_out;

    const size_t szLh   = (size_t)V * V * sizeof(_Float16);          // 302 MB
    const size_t szTh   = (size_t)CIN * V * sizeof(_Float16);        // 384 KB
    const size_t szPart = (size_t)SSPLIT * CIN * V * sizeof(float);  // 6 MB
    const size_t szT    = (size_t)4 * CIN * V * sizeof(float);       // 3 MB
    const bool fast = ws_size >= szLh + szTh + szPart + szT;

    char* ws = (char*)d_ws;
    _Float16* Lh = (_Float16*)ws;
    char* p = ws + (fast ? szLh : 0);
    _Float16* Th = (_Float16*)p;          p += szTh;
    float*    partials = (float*)p;       p += szPart;
    float*    Tf = (float*)p;             // T_1..T_4

    const dim3 mmGrid(192, SSPLIT);

    x_to_h<<<768, 256, 0, stream>>>(x, Th);

    // pass 1: T_1 = x @ L^T   (reads f32 L, writes fp16 Lh on fast path)
    if (fast)
        cheb_mm<true, true><<<mmGrid, 256, 0, stream>>>(Th, L, nullptr, Lh, partials);
    else
        cheb_mm<true, false><<<mmGrid, 256, 0, stream>>>(Th, L, nullptr, nullptr, partials);
    cheb_reduce<<<768, 256, 0, stream>>>(partials, nullptr, Tf, Th, 1);

    // passes 2..4
    for (int k = 2; k <= 4; ++k) {
        if (fast)
            cheb_mm<false, false><<<mmGrid, 256, 0, stream>>>(Th, nullptr, Lh, nullptr, partials);
        else
            cheb_mm<true, false><<<mmGrid, 256, 0, stream>>>(Th, L, nullptr, nullptr, partials);
        const float* Tm2 = (k == 2) ? x : Tf + (size_t)(k - 3) * CIN * V;
        cheb_reduce<<<768, 256, 0, stream>>>(partials, Tm2,
                                             Tf + (size_t)(k - 1) * CIN * V, Th, k);
    }

    cheb_out_k<<<dim3(V / 256, COUT), 256, 0, stream>>>(x, Tf, W, bias, out);
}

// Round 2
// 404.254 us; speedup vs baseline: 1.2235x; 1.2235x over previous
//
#include <hip/hip_runtime.h>

#define V 12288
#define CIN 16
#define COUT 32
#define NK 5
#define SSPLIT 8
#define UCHUNK (V / SSPLIT)     // 1536
#define NSTEP (UCHUNK / 32)     // 48 MFMA k-steps per chunk
#define NVT (V / 16)            // 768 v-tiles
#define NM (NVT * SSPLIT)       // 6144 wave-streams

typedef _Float16 half8 __attribute__((ext_vector_type(8)));
typedef float f32x4 __attribute__((ext_vector_type(4)));

// One wave owns one 16x16 (i x v) tile for one u-chunk. A and B fragments use
// the identical (lane,reg)->k mapping so any HW K permutation cancels.
// C/D: i = (lane>>4)*4 + reg, v = v0 + (lane&15)  [m89].
//
// MODE 0: pass 1 fast  — A from f32 x, L from f32 row-major; converts the B
//         fragment to fp16 and stores it to Lh in FRAGMENT-TILED order:
//         halfs [tile*512, tile*512+512), lane l at +l*8. tile = m*NSTEP + s.
// MODE 1: passes 2-4 fast — A from fp16 Th, B streamed from tiled Lh:
//         fully contiguous 1KB/wave-instruction, 48KB contiguous per wave.
// MODE 2: fallback — L from f32 row-major every pass, no store.
template<int MODE, bool AF32>
__global__ __launch_bounds__(256) void cheb_mm(
    const void*     __restrict__ Av,      // x (f32) or Th (fp16), (CIN,V)
    const float*    __restrict__ Lf,      // (V,V) f32
    const _Float16* __restrict__ Lh,      // tiled fp16
    _Float16*       __restrict__ Lh_out,  // tiled fp16 (MODE 0)
    float*          __restrict__ partials,// (SSPLIT,CIN,V)
    int rev)                              // serpentine direction
{
    const int wave = threadIdx.x >> 6;
    const int lane = threadIdx.x & 63;
    const int lr = lane & 15;
    const int hi = lane >> 4;

    int m = (blockIdx.x * 4 + wave) * SSPLIT + blockIdx.y;
    if (rev) m = NM - 1 - m;
    const int vt = m / SSPLIT;
    const int uc = m % SSPLIT;
    const int v0 = vt * 16;
    const int u0 = uc * UCHUNK;

    f32x4 acc = {0.f, 0.f, 0.f, 0.f};

    if constexpr (MODE == 1) {
        const _Float16* ap = (const _Float16*)Av + (size_t)lr * V + u0 + hi * 8;
        const _Float16* lp = Lh + (size_t)m * (NSTEP * 512) + lane * 8;
        #pragma unroll 8
        for (int s = 0; s < NSTEP; ++s) {
            const int sq = rev ? (NSTEP - 1 - s) : s;
            half8 a = *(const half8*)(ap + sq * 32);
            half8 b = *(const half8*)(lp + (size_t)sq * 512);
            acc = __builtin_amdgcn_mfma_f32_16x16x32_f16(a, b, acc, 0, 0, 0);
        }
    } else {
        const float* lp = Lf + (size_t)(v0 + lr) * V + u0 + hi * 8;
        const void* apv;
        if constexpr (AF32) apv = (const float*)Av + (size_t)lr * V + u0 + hi * 8;
        else                apv = (const _Float16*)Av + (size_t)lr * V + u0 + hi * 8;
        _Float16* lo = nullptr;
        if constexpr (MODE == 0) lo = Lh_out + (size_t)m * (NSTEP * 512) + lane * 8;
        #pragma unroll 4
        for (int s = 0; s < NSTEP; ++s) {
            const int sq = rev ? (NSTEP - 1 - s) : s;
            half8 a;
            if constexpr (AF32) {
                f32x4 a0 = *(const f32x4*)((const float*)apv + sq * 32);
                f32x4 a1 = *(const f32x4*)((const float*)apv + sq * 32 + 4);
                #pragma unroll
                for (int j = 0; j < 4; ++j) {
                    a[j]     = (_Float16)a0[j];
                    a[j + 4] = (_Float16)a1[j];
                }
            } else {
                a = *(const half8*)((const _Float16*)apv + sq * 32);
            }
            f32x4 f0 = *(const f32x4*)(lp + sq * 32);
            f32x4 f1 = *(const f32x4*)(lp + sq * 32 + 4);
            half8 b;
            #pragma unroll
            for (int j = 0; j < 4; ++j) {
                b[j]     = (_Float16)f0[j];
                b[j + 4] = (_Float16)f1[j];
            }
            if constexpr (MODE == 0) *(half8*)(lo + (size_t)sq * 512) = b;
            acc = __builtin_amdgcn_mfma_f32_16x16x32_f16(a, b, acc, 0, 0, 0);
        }
    }

    float* pp = partials + ((size_t)uc * CIN + hi * 4) * V + v0 + lr;
    pp[0]           = acc[0];
    pp[(size_t)V]   = acc[1];
    pp[(size_t)2*V] = acc[2];
    pp[(size_t)3*V] = acc[3];
}

// ---- reduce partials, apply recurrence, emit f32 + fp16 -------------------
__global__ __launch_bounds__(256) void cheb_reduce(
    const float* __restrict__ partials,
    const float* __restrict__ Tm2,        // T_{k-2} (f32), unused for k==1
    float*       __restrict__ Tk,
    _Float16*    __restrict__ Th,
    int k)
{
    int i = blockIdx.x * 256 + threadIdx.x;   // CIN*V exact
    float s = 0.f;
    #pragma unroll
    for (int j = 0; j < SSPLIT; ++j) s += partials[(size_t)j * CIN * V + i];
    float t = (k == 1) ? s : 2.f * s - Tm2[i];
    Tk[i] = t;
    Th[i] = (_Float16)t;
}

// ---- out(o,v) = bias(o) + sum_k sum_i T_k(i,v) * W(k,i,o) -----------------
__global__ __launch_bounds__(256) void cheb_out_k(
    const float* __restrict__ x,      // T_0
    const float* __restrict__ T14,    // T_1..T_4, (4,CIN,V)
    const float* __restrict__ W,      // (NK,CIN,COUT)
    const float* __restrict__ bias,
    float* __restrict__ out)
{
    int v = blockIdx.x * 256 + threadIdx.x;
    int o = blockIdx.y;
    float acc = bias[o];
    #pragma unroll
    for (int i = 0; i < CIN; ++i)
        acc += x[(size_t)i * V + v] * W[i * COUT + o];
    #pragma unroll
    for (int k = 1; k < NK; ++k)
        #pragma unroll
        for (int i = 0; i < CIN; ++i)
            acc += T14[((size_t)(k - 1) * CIN + i) * V + v] * W[(k * CIN + i) * COUT + o];
    out[(size_t)o * V + v] = acc;
}

extern "C" void kernel_launch(void* const* d_in, const int* in_sizes, int n_in,
                              void* d_out, int out_size, void* d_ws, size_t ws_size,
                              hipStream_t stream) {
    const float* x    = (const float*)d_in[0];
    const float* L    = (const float*)d_in[1];
    const float* W    = (const float*)d_in[2];
    const float* bias = (const float*)d_in[3];
    float* out = (float*)d_out;

    const size_t szLh   = (size_t)V * V * sizeof(_Float16);          // 302 MB
    const size_t szTh   = (size_t)CIN * V * sizeof(_Float16);        // 384 KB
    const size_t szPart = (size_t)SSPLIT * CIN * V * sizeof(float);  // 6 MB
    const size_t szT    = (size_t)4 * CIN * V * sizeof(float);       // 3 MB
    const bool fast = ws_size >= szLh + szTh + szPart + szT;

    char* ws = (char*)d_ws;
    _Float16* Lh = (_Float16*)ws;
    char* p = ws + (fast ? szLh : 0);
    _Float16* Th = (_Float16*)p;          p += szTh;
    float*    partials = (float*)p;       p += szPart;
    float*    Tf = (float*)p;             // T_1..T_4

    const dim3 mmGrid(NVT / 4, SSPLIT);   // 192 x 8 = 1536 blocks

    // pass 1: T_1 = x @ L^T ; reads f32 x + f32 L, emits fragment-tiled Lh
    if (fast)
        cheb_mm<0, true><<<mmGrid, 256, 0, stream>>>(x, L, nullptr, Lh, partials, 0);
    else
        cheb_mm<2, true><<<mmGrid, 256, 0, stream>>>(x, L, nullptr, nullptr, partials, 0);
    cheb_reduce<<<768, 256, 0, stream>>>(partials, nullptr, Tf, Th, 1);

    // passes 2..4, serpentine (pass2 reversed, pass3 forward, pass4 reversed)
    for (int k = 2; k <= 4; ++k) {
        const int rev = (k & 1) ? 0 : 1;
        if (fast)
            cheb_mm<1, false><<<mmGrid, 256, 0, stream>>>(Th, nullptr, Lh, nullptr, partials, rev);
        else
            cheb_mm<2, false><<<mmGrid, 256, 0, stream>>>(Th, L, nullptr, nullptr, partials, rev);
        const float* Tm2 = (k == 2) ? x : Tf + (size_t)(k - 3) * CIN * V;
        cheb_reduce<<<768, 256, 0, stream>>>(partials, Tm2,
                                             Tf + (size_t)(k - 1) * CIN * V, Th, k);
    }

    cheb_out_k<<<dim3(V / 256, COUT), 256, 0, stream>>>(x, Tf, W, bias, out);
}